// Round 3
// baseline (2040.474 us; speedup 1.0000x reference)
//
#include <hip/hip_runtime.h>
#include <cstddef>

// Problem constants (reference: B=8, S=512, E=128, H=512, ENC=128)
#define BB 8
#define SS 512
#define EE 128
#define HH 512
#define ENC 128

// ---------------------------------------------------------------------------
// Bit-exact emulation of XLA CPU's EmitTanh (verified bitwise r6..r15).
// All ops rn, NON-fused. __f*_rn intrinsics block compiler contraction.
// NOTE (r8): packed v_pk_* fp32 is NOT bit-identical on gfx950 — scalar only.
// ---------------------------------------------------------------------------
__device__ __forceinline__ float xla_tanhf(float x) {
    const float cx = fminf(fmaxf(x, -9.0f), 9.0f);
    const float x2 = __fmul_rn(cx, cx);
    float p = -2.76076847742355e-16f;
    p = __fadd_rn(__fmul_rn(p, x2), 2.00018790482477e-13f);
    p = __fadd_rn(__fmul_rn(p, x2), -8.60467152213735e-11f);
    p = __fadd_rn(__fmul_rn(p, x2), 5.12229709037114e-08f);
    p = __fadd_rn(__fmul_rn(p, x2), 1.48572235717979e-05f);
    p = __fadd_rn(__fmul_rn(p, x2), 6.37261928875436e-04f);
    p = __fadd_rn(__fmul_rn(p, x2), 4.89352455891786e-03f);
    const float num = __fmul_rn(cx, p);
    float q = 1.19825839466702e-06f;
    q = __fadd_rn(__fmul_rn(q, x2), 1.18534705686654e-04f);
    q = __fadd_rn(__fmul_rn(q, x2), 2.26843463243900e-03f);
    q = __fadd_rn(__fmul_rn(q, x2), 4.89352518554385e-03f);
    const float r = __fdiv_rn(num, q);
    return (fabsf(x) < 0.0004f) ? x : r;
}

// Map a packed chunk-row m -> global action row:
//   b = m >> chsh (CH = chm1+1), global row = b*SS + i0 + (m & chm1)
__device__ __forceinline__ int arow_map(int m, int chm1, int chsh, int i0) {
    return ((m >> chsh) * SS) + i0 + (m & chm1);
}

// ---------------------------------------------------------------------------
// Tiled GEMM body, bitwise-preserving XLA-CPU dot semantics (VERIFIED
// r6..r18 — scalar v_mul/v_add only). K-chain: one accumulator per element,
// k0 tiles ascend, inner k ascends — DO NOT TOUCH.
//
// TRANSP=1 (GEMM2 only): block bx covers B-rows o = d*128+e with
// d in [16*bd,16*bd+16), e in [8*be,8*be+8)  (bd=bx>>4, be=bx&15).
// Epilogue stores the d-INTERLEAVED layout:
//   Wa4[m][(d>>2)*128 + e] as float4 component (d&3)
// so the scan's quarter loads are lane-consecutive float4 (r15-proven).
// Values bit-identical; address-only.
// ---------------------------------------------------------------------------
template <int ACT, int MAPROW, int TRANSP>
__device__ __forceinline__ void gemm_body(const float* __restrict__ A,
                                          const float* __restrict__ Bm,
                                          const float* __restrict__ bias,
                                          float* __restrict__ C,
                                          int N, int K,
                                          int chm1, int chsh, int i0,
                                          int bx, int by,
                                          float (*As)[128], float (*Bs)[128]) {
    const int tid = threadIdx.x;
    const int tx = tid & 15;   // n-direction (8 cols each)
    const int ty = tid >> 4;   // m-direction (8 rows each)
    const int n0 = bx * 128;
    const int m0 = by * 128;
    const int bd = bx >> 4;   // TRANSP: d-tile (0..7)
    const int be = bx & 15;   // TRANSP: e-tile (0..15)

    const int lr = tid >> 2;          // 0..63 (row within tile)
    const int lc = (tid & 3) << 2;    // 0,4,8,12 (col within K-tile)

    const int ga0 = MAPROW ? arow_map(m0 + lr, chm1, chsh, i0) : (m0 + lr);
    const int ga1 = MAPROW ? arow_map(m0 + lr + 64, chm1, chsh, i0) : (m0 + lr + 64);

    // B-row indices for the two loader rows (identity unless TRANSP)
    const int r0 = lr, r1 = lr + 64;
    const int gb0 = TRANSP ? ((bd * 16 + (r0 >> 3)) * 128 + be * 8 + (r0 & 7))
                           : (n0 + r0);
    const int gb1 = TRANSP ? ((bd * 16 + (r1 >> 3)) * 128 + be * 8 + (r1 & 7))
                           : (n0 + r1);

    float acc[8][8];
#pragma unroll
    for (int i = 0; i < 8; ++i)
#pragma unroll
        for (int j = 0; j < 8; ++j) acc[i][j] = 0.f;

    for (int k0 = 0; k0 < K; k0 += 16) {
        const float4 a0 = *(const float4*)(A + (size_t)ga0 * K + (k0 + lc));
        const float4 a1 = *(const float4*)(A + (size_t)ga1 * K + (k0 + lc));
        const float4 b0 = *(const float4*)(Bm + (size_t)gb0 * K + (k0 + lc));
        const float4 b1 = *(const float4*)(Bm + (size_t)gb1 * K + (k0 + lc));

        __syncthreads();  // previous iteration's compute done before overwrite

        As[lc + 0][lr] = a0.x; As[lc + 1][lr] = a0.y;
        As[lc + 2][lr] = a0.z; As[lc + 3][lr] = a0.w;
        As[lc + 0][lr + 64] = a1.x; As[lc + 1][lr + 64] = a1.y;
        As[lc + 2][lr + 64] = a1.z; As[lc + 3][lr + 64] = a1.w;
        Bs[lc + 0][lr] = b0.x; Bs[lc + 1][lr] = b0.y;
        Bs[lc + 2][lr] = b0.z; Bs[lc + 3][lr] = b0.w;
        Bs[lc + 0][lr + 64] = b1.x; Bs[lc + 1][lr + 64] = b1.y;
        Bs[lc + 2][lr + 64] = b1.z; Bs[lc + 3][lr + 64] = b1.w;

        __syncthreads();

#pragma unroll
        for (int k = 0; k < 16; ++k) {   // ascending k within tile
            const float4 av0 = *(const float4*)&As[k][ty * 8];
            const float4 av1 = *(const float4*)&As[k][ty * 8 + 4];
            const float4 bv0 = *(const float4*)&Bs[k][tx * 8];
            const float4 bv1 = *(const float4*)&Bs[k][tx * 8 + 4];
            const float a[8] = {av0.x, av0.y, av0.z, av0.w, av1.x, av1.y, av1.z, av1.w};
            const float b[8] = {bv0.x, bv0.y, bv0.z, bv0.w, bv1.x, bv1.y, bv1.z, bv1.w};
#pragma unroll
            for (int i = 0; i < 8; ++i)
#pragma unroll
                for (int j = 0; j < 8; ++j)
                    acc[i][j] = __fadd_rn(acc[i][j], __fmul_rn(a[i], b[j]));
        }
    }

    // epilogue: + bias (after full k-chain), optional XLA tanh, store
#pragma unroll
    for (int i = 0; i < 8; ++i) {
        const int m = m0 + ty * 8 + i;
        if (TRANSP) {
            // acc[i][j] is element o = d*128 + e, d = bd*16+tx, e = be*8+j.
            // d-interleaved store: C[m][((d>>2)*128 + e)*4 + (d&3)]
            const int d = bd * 16 + tx;
#pragma unroll
            for (int j = 0; j < 8; ++j) {
                const int ee = be * 8 + j;
                const int o = d * 128 + ee;
                const float v = __fadd_rn(acc[i][j], bias[o]);
                C[(size_t)m * N + ((size_t)(d >> 2) * 128 + ee) * 4 + (d & 3)] = v;
            }
        } else {
            float v[8];
#pragma unroll
            for (int j = 0; j < 8; ++j) {
                const int n = n0 + tx * 8 + j;
                v[j] = __fadd_rn(acc[i][j], bias[n]);
                if (ACT) v[j] = xla_tanhf(v[j]);
            }
            float4* dst = (float4*)(C + (size_t)m * N + (n0 + tx * 8));
            dst[0] = make_float4(v[0], v[1], v[2], v[3]);
            dst[1] = make_float4(v[4], v[5], v[6], v[7]);
        }
    }
}

template <int ACT, int MAPROW, int TRANSP>
__global__ __launch_bounds__(256) void gemm_nt(const float* __restrict__ A,
                                               const float* __restrict__ Bm,
                                               const float* __restrict__ bias,
                                               float* __restrict__ C,
                                               int N, int K,
                                               int chm1, int chsh, int i0) {
    __shared__ float As[16][128];
    __shared__ float Bs[16][128];
    gemm_body<ACT, MAPROW, TRANSP>(A, Bm, bias, C, N, K, chm1, chsh, i0,
                                   blockIdx.x, blockIdx.y, As, Bs);
}

// ---------------------------------------------------------------------------
// Sequential attractor scan body — r19 structure:
//   * prefetch distance FOUR quarters (one full step), consume-then-prefetch
//     into the SAME named buffer (period = 1 step, all indices static).
//   * NO clamp: monotone cursor Pf += 1024 float4/quarter. Prefetch runs up
//     to 4 quarters (64 KB) past the chunk — Wa buffers are PADDED by 64 KB,
//     so all loads hit allocated memory; overrun values are never consumed.
//   * chain unchanged, op-for-op the verified sequence: ONE accumulator,
//     strictly ascending d (q asc, dq asc, x,y,z,w) — bitwise contract.
// VGPR: 4x8 float4 = 128 buffer + ~20 misc ≈ 150.
// ---------------------------------------------------------------------------
#define SCAN_Q4(Q, BUF)                                                     \
    {                                                                       \
        /* consume quarter Q: d = 32Q .. 32Q+31, strictly ascending */      \
        _Pragma("unroll")                                                   \
        for (int dq = 0; dq < 8; ++dq) {                                    \
            const float4 t4 = *(const float4*)&et[s][(Q) * 32 + dq * 4];    \
            const float4 wv = BUF[dq]; /* W[d..d+3][e], d = 32Q+4dq */      \
            sum = __fadd_rn(sum, __fmul_rn(t4.x, wv.x));                    \
            sum = __fadd_rn(sum, __fmul_rn(t4.y, wv.y));                    \
            sum = __fadd_rn(sum, __fmul_rn(t4.z, wv.z));                    \
            sum = __fadd_rn(sum, __fmul_rn(t4.w, wv.w));                    \
        }                                                                   \
        /* refill BUF with the quarter 4 ahead (straight-line, no clamp) */ \
        _Pragma("unroll")                                                   \
        for (int u = 0; u < 8; ++u) BUF[u] = Pf[u * 128];                   \
        Pf += 1024;                                                         \
        asm volatile("" ::: "memory");                                      \
    }

__device__ __forceinline__ void scan_body(const float* __restrict__ Wa,
                                          const float* __restrict__ e0,
                                          float* __restrict__ et_state,
                                          float* __restrict__ out,
                                          int i0, int CH, int b,
                                          float (*et)[128]) {
    const int e = threadIdx.x & 127;  // 0..127 (callers ensure 128 threads)

    int s = 0;
    if (i0 == 0) {
        const float v = e0[e];
        et[0][e] = v;
        out[(size_t)b * SS * ENC + e] = v;
    } else {
        et[0][e] = et_state[b * 128 + e];
    }
    __syncthreads();

    const int start = (i0 == 0) ? 1 : 0;
    const float4* Wb4 = (const float4*)(Wa + (size_t)b * CH * (ENC * ENC));
    // step stride in float4: ENC*ENC/4 = 4096; quarter stride: 8*128 = 1024

    // 4 quarter buffers x 8 float4 = 128 VGPRs; preload quarters 0..3 of
    // step `start` (one full step in flight).
    float4 w0[8], w1[8], w2[8], w3[8];
    const float4* Pq = Wb4 + (size_t)start * 4096 + e;
#pragma unroll
    for (int u = 0; u < 8; ++u) w0[u] = Pq[u * 128];
#pragma unroll
    for (int u = 0; u < 8; ++u) w1[u] = Pq[(8 + u) * 128];
#pragma unroll
    for (int u = 0; u < 8; ++u) w2[u] = Pq[(16 + u) * 128];
#pragma unroll
    for (int u = 0; u < 8; ++u) w3[u] = Pq[(24 + u) * 128];
    const float4* Pf = Pq + 4096;   // prefetch cursor: quarter 4
    asm volatile("" ::: "memory");  // loads pinned before first chain

    for (int ii = start; ii < CH; ++ii) {
        float sum = 0.f;   // ONE accumulator, ascending d across all quarters
        SCAN_Q4(0, w0)
        SCAN_Q4(1, w1)
        SCAN_Q4(2, w2)
        SCAN_Q4(3, w3)
        const float v = fminf(fmaxf(sum, -5.f), 5.f);  // jnp.clip
        out[((size_t)b * SS + (i0 + ii)) * ENC + e] = v;
        et[s ^ 1][e] = v;   // this step's readers use et[s] — no conflict
        __syncthreads();    // publishes et[s^1]; orders next step's overwrite
        s ^= 1;
    }
    et_state[b * 128 + e] = et[s][e];
}

// Standalone scan (tail chunk / serial fallback): 128 threads, 1 block/CU.
__global__ __launch_bounds__(128, 1) void scan_kernel(const float* __restrict__ Wa,
                                                      const float* __restrict__ e0,
                                                      float* __restrict__ et_state,
                                                      float* __restrict__ out,
                                                      int i0, int CH) {
    __shared__ float et[2][128];
    scan_body(Wa, e0, et_state, out, i0, CH, blockIdx.x, et);
}

// ---------------------------------------------------------------------------
// r19 combined kernel: blocks (x<8, y==0) run the scan of chunk c (2 waves,
// waves 2/3 exit whole — halves scan load traffic vs r18's duplication and
// removes redundant prio-2 waves); blocks x>=8 run GEMM2 of chunk c+1.
// Halves are independent (scan c reads WaSrc from the previous launch;
// GEMM2 reads hidden written before this launch) — dispatch-order safe.
// __launch_bounds__(256,3): VGPR cap 170 — fits the scan's ~150-reg
// distance-4 pipeline WITHOUT spill, GEMM2 keeps 3 resident blocks/CU.
// ---------------------------------------------------------------------------
__global__ __launch_bounds__(256, 3) void gemm2_scan(
        const float* __restrict__ hidden, const float* __restrict__ W2,
        const float* __restrict__ b2, float* __restrict__ WaDst,
        const float* __restrict__ WaSrc, const float* __restrict__ e0,
        float* __restrict__ et_state, float* __restrict__ out,
        int i0_scan, int CH) {
    __shared__ float As[16][128];
    __shared__ float Bs[16][128];
    __shared__ float et[2][128];

    if (blockIdx.x < 8) {
        if (blockIdx.y != 0) return;     // only the y==0 row carries scan
        if (threadIdx.x >= 128) return;  // waves 2,3 exit whole (barrier-safe)
        __builtin_amdgcn_s_setprio(2);   // favor the serial chain on its CU
        scan_body(WaSrc, e0, et_state, out, i0_scan, CH, blockIdx.x, et);
        return;
    }
    // GEMM2 half: hidden is PACKED per-chunk (MAPROW=0), Wa d-interleaved.
    gemm_body<0, 0, 1>(hidden, W2, b2, WaDst, ENC * ENC, HH,
                       0, 0, 0, blockIdx.x - 8, blockIdx.y, As, Bs);
}

// ---------------------------------------------------------------------------
extern "C" void kernel_launch(void* const* d_in, const int* in_sizes, int n_in,
                              void* d_out, int out_size, void* d_ws, size_t ws_size,
                              hipStream_t stream) {
    const float* A  = (const float*)d_in[0];  // (B,S,E)   = (8,512,128) fp32
    const float* W1 = (const float*)d_in[1];  // (H,E)     = (512,128)  fp32
    const float* b1 = (const float*)d_in[2];  // (H,)      fp32
    const float* W2 = (const float*)d_in[3];  // (ENC*ENC,H) = (16384,512) fp32
    const float* b2 = (const float*)d_in[4];  // (ENC*ENC,) fp32
    const float* e0 = (const float*)d_in[5];  // (1,ENC)   fp32
    float* out = (float*)d_out;               // (B,S,ENC) fp32

    // ---- r19 pipelined path: CH=128, per-chunk hidden (single 2MB buffer),
    //      double-buffered PADDED Wa chunks. ----
    const int CH = 128;
    const int n = SS / CH;                     // 4 chunks
    const int Mc = BB * CH;                    // 1024 rows
    const size_t hid_bytes = (size_t)Mc * HH * sizeof(float);           // 2 MB
    const size_t chunk_elems = (size_t)Mc * (ENC * ENC);                // f32
    const size_t wa_pad_bytes = chunk_elems * sizeof(float) + 65536;    // +64KB
    const size_t need = 4096 + hid_bytes + 2 * wa_pad_bytes;  // ~136.45 MB

    if (need <= ws_size) {
        float* et_state = (float*)d_ws;
        float* hidden   = (float*)((char*)d_ws + 4096);
        float* Wa0 = (float*)((char*)hidden + hid_bytes);
        float* Wa1 = (float*)((char*)Wa0 + wa_pad_bytes);
        float* Wab[2] = {Wa0, Wa1};

        const int chm1 = CH - 1;   // 127
        const int chsh = 7;        // log2(128)

        dim3 g1(HH / 128, Mc / 128);               // (4, 8)
        dim3 g2((ENC * ENC) / 128, Mc / 128);      // (128, 8)
        dim3 gc(8 + (ENC * ENC) / 128, Mc / 128);  // (136, 8)

        // Prologue: hidden(0), Wa(0)
        gemm_nt<1, 1, 0><<<g1, 256, 0, stream>>>(A, W1, b1, hidden, HH, EE,
                                                 chm1, chsh, 0);
        gemm_nt<0, 0, 1><<<g2, 256, 0, stream>>>(hidden, W2, b2, Wa0,
                                                 ENC * ENC, HH, 0, 0, 0);
        // Pipeline: G1(c+1); L_c = { scan chunk c || GEMM2 chunk c+1 }.
        // Stream order guarantees: Wa(c) complete before L_c; L_{c-1} done
        // before G1(c+1) overwrites hidden; scan(c) done before GEMM2(c+2)
        // reuses Wab[c&1].
        for (int c = 0; c < n; ++c) {
            if (c + 1 < n) {
                gemm_nt<1, 1, 0><<<g1, 256, 0, stream>>>(A, W1, b1, hidden,
                                                         HH, EE, chm1, chsh,
                                                         (c + 1) * CH);
                gemm2_scan<<<gc, 256, 0, stream>>>(hidden, W2, b2,
                                                   Wab[(c + 1) & 1],
                                                   Wab[c & 1],
                                                   e0, et_state, out,
                                                   c * CH, CH);
            } else {
                scan_kernel<<<BB, 128, 0, stream>>>(Wab[c & 1], e0, et_state,
                                                    out, c * CH, CH);
            }
        }
        return;
    }

    // ---- Legacy serial fallback (tiny workspace): r16 schedule. ----
    // (+64KB slack in `need` for the scan's unclamped 4-quarter overrun.)
    int CHs = 16;
    for (int c = 512; c >= 16; c >>= 1) {
        const size_t Mcs = (size_t)BB * c;
        const size_t ned = 4096 + Mcs * HH * sizeof(float) +
                           Mcs * (size_t)(ENC * ENC) * sizeof(float) + 65536;
        if (ned <= ws_size) { CHs = c; break; }
    }
    const int Mcs = BB * CHs;
    int chsh = 0;
    while ((1 << chsh) < CHs) ++chsh;
    const int chm1 = CHs - 1;

    float* et_state = (float*)d_ws;
    float* hidden   = (float*)((char*)d_ws + 4096);
    float* Wa       = hidden + (size_t)Mcs * HH;

    for (int i0 = 0; i0 < SS; i0 += CHs) {
        dim3 g1(HH / 128, Mcs / 128);
        gemm_nt<1, 1, 0><<<g1, 256, 0, stream>>>(A, W1, b1, hidden, HH, EE,
                                                 chm1, chsh, i0);
        dim3 g2((ENC * ENC) / 128, Mcs / 128);
        gemm_nt<0, 0, 1><<<g2, 256, 0, stream>>>(hidden, W2, b2, Wa, ENC * ENC,
                                                 HH, 0, 0, 0);
        scan_kernel<<<BB, 128, 0, stream>>>(Wa, e0, et_state, out, i0, CHs);
    }
}

// Round 4
// 1657.777 us; speedup vs baseline: 1.2309x; 1.2309x over previous
//
#include <hip/hip_runtime.h>
#include <cstddef>

// Problem constants (reference: B=8, S=512, E=128, H=512, ENC=128)
#define BB 8
#define SS 512
#define EE 128
#define HH 512
#define ENC 128

// ---------------------------------------------------------------------------
// Bit-exact emulation of XLA CPU's EmitTanh (verified bitwise r6..r15).
// All ops rn, NON-fused. __f*_rn intrinsics block compiler contraction.
// NOTE (r8): packed v_pk_* fp32 is NOT bit-identical on gfx950 — scalar only.
// ---------------------------------------------------------------------------
__device__ __forceinline__ float xla_tanhf(float x) {
    const float cx = fminf(fmaxf(x, -9.0f), 9.0f);
    const float x2 = __fmul_rn(cx, cx);
    float p = -2.76076847742355e-16f;
    p = __fadd_rn(__fmul_rn(p, x2), 2.00018790482477e-13f);
    p = __fadd_rn(__fmul_rn(p, x2), -8.60467152213735e-11f);
    p = __fadd_rn(__fmul_rn(p, x2), 5.12229709037114e-08f);
    p = __fadd_rn(__fmul_rn(p, x2), 1.48572235717979e-05f);
    p = __fadd_rn(__fmul_rn(p, x2), 6.37261928875436e-04f);
    p = __fadd_rn(__fmul_rn(p, x2), 4.89352455891786e-03f);
    const float num = __fmul_rn(cx, p);
    float q = 1.19825839466702e-06f;
    q = __fadd_rn(__fmul_rn(q, x2), 1.18534705686654e-04f);
    q = __fadd_rn(__fmul_rn(q, x2), 2.26843463243900e-03f);
    q = __fadd_rn(__fmul_rn(q, x2), 4.89352518554385e-03f);
    const float r = __fdiv_rn(num, q);
    return (fabsf(x) < 0.0004f) ? x : r;
}

// Map a packed chunk-row m -> global action row:
//   b = m >> chsh (CH = chm1+1), global row = b*SS + i0 + (m & chm1)
__device__ __forceinline__ int arow_map(int m, int chm1, int chsh, int i0) {
    return ((m >> chsh) * SS) + i0 + (m & chm1);
}

// ---------------------------------------------------------------------------
// Tiled GEMM, bitwise-preserving XLA-CPU dot semantics (VERIFIED r6..r19 —
// scalar v_mul/v_add only). GEMM2 measured at its scalar-VALU floor
// (~437 us/chunk @CH=256, VALUBusy ~64%). K-chain: one accumulator per
// element, k0 tiles ascend, inner k ascends — DO NOT TOUCH.
//
// TRANSP=1 (GEMM2 only): block bx covers B-rows o = d*128+e with
// d in [16*bd,16*bd+16), e in [8*be,8*be+8)  (bd=bx>>4, be=bx&15).
// Epilogue stores the d-INTERLEAVED layout:
//   Wa4[m][(d>>2)*128 + e] as float4 component (d&3)
// so the scan's quarter loads are lane-consecutive float4 (r15-proven).
// Values bit-identical; address-only.
//
// r20: combined gemm2_scan kernel REMOVED — three rounds (r17 88-reg spill,
// r18 contention, r19 84-reg spill + 3x scratch traffic) showed co-compiling
// the register-heavy scan with GEMM2 makes scan codegen fragile (rule #19).
// Serial schedule restored; the scan itself is the optimization target.
// ---------------------------------------------------------------------------
template <int ACT, int MAPROW, int TRANSP>
__global__ __launch_bounds__(256) void gemm_nt(const float* __restrict__ A,
                                               const float* __restrict__ Bm,
                                               const float* __restrict__ bias,
                                               float* __restrict__ C,
                                               int N, int K,
                                               int chm1, int chsh, int i0) {
    __shared__ float As[16][128];
    __shared__ float Bs[16][128];

    const int tid = threadIdx.x;
    const int tx = tid & 15;   // n-direction (8 cols each)
    const int ty = tid >> 4;   // m-direction (8 rows each)
    const int n0 = blockIdx.x * 128;
    const int m0 = blockIdx.y * 128;
    const int bd = blockIdx.x >> 4;   // TRANSP: d-tile (0..7)
    const int be = blockIdx.x & 15;   // TRANSP: e-tile (0..15)

    const int lr = tid >> 2;          // 0..63 (row within tile)
    const int lc = (tid & 3) << 2;    // 0,4,8,12 (col within K-tile)

    const int ga0 = MAPROW ? arow_map(m0 + lr, chm1, chsh, i0) : (m0 + lr);
    const int ga1 = MAPROW ? arow_map(m0 + lr + 64, chm1, chsh, i0) : (m0 + lr + 64);

    // B-row indices for the two loader rows (identity unless TRANSP)
    const int r0 = lr, r1 = lr + 64;
    const int gb0 = TRANSP ? ((bd * 16 + (r0 >> 3)) * 128 + be * 8 + (r0 & 7))
                           : (n0 + r0);
    const int gb1 = TRANSP ? ((bd * 16 + (r1 >> 3)) * 128 + be * 8 + (r1 & 7))
                           : (n0 + r1);

    float acc[8][8];
#pragma unroll
    for (int i = 0; i < 8; ++i)
#pragma unroll
        for (int j = 0; j < 8; ++j) acc[i][j] = 0.f;

    for (int k0 = 0; k0 < K; k0 += 16) {
        const float4 a0 = *(const float4*)(A + (size_t)ga0 * K + (k0 + lc));
        const float4 a1 = *(const float4*)(A + (size_t)ga1 * K + (k0 + lc));
        const float4 b0 = *(const float4*)(Bm + (size_t)gb0 * K + (k0 + lc));
        const float4 b1 = *(const float4*)(Bm + (size_t)gb1 * K + (k0 + lc));

        __syncthreads();  // previous iteration's compute done before overwrite

        As[lc + 0][lr] = a0.x; As[lc + 1][lr] = a0.y;
        As[lc + 2][lr] = a0.z; As[lc + 3][lr] = a0.w;
        As[lc + 0][lr + 64] = a1.x; As[lc + 1][lr + 64] = a1.y;
        As[lc + 2][lr + 64] = a1.z; As[lc + 3][lr + 64] = a1.w;
        Bs[lc + 0][lr] = b0.x; Bs[lc + 1][lr] = b0.y;
        Bs[lc + 2][lr] = b0.z; Bs[lc + 3][lr] = b0.w;
        Bs[lc + 0][lr + 64] = b1.x; Bs[lc + 1][lr + 64] = b1.y;
        Bs[lc + 2][lr + 64] = b1.z; Bs[lc + 3][lr + 64] = b1.w;

        __syncthreads();

#pragma unroll
        for (int k = 0; k < 16; ++k) {   // ascending k within tile
            const float4 av0 = *(const float4*)&As[k][ty * 8];
            const float4 av1 = *(const float4*)&As[k][ty * 8 + 4];
            const float4 bv0 = *(const float4*)&Bs[k][tx * 8];
            const float4 bv1 = *(const float4*)&Bs[k][tx * 8 + 4];
            const float a[8] = {av0.x, av0.y, av0.z, av0.w, av1.x, av1.y, av1.z, av1.w};
            const float b[8] = {bv0.x, bv0.y, bv0.z, bv0.w, bv1.x, bv1.y, bv1.z, bv1.w};
#pragma unroll
            for (int i = 0; i < 8; ++i)
#pragma unroll
                for (int j = 0; j < 8; ++j)
                    acc[i][j] = __fadd_rn(acc[i][j], __fmul_rn(a[i], b[j]));
        }
    }

    // epilogue: + bias (after full k-chain), optional XLA tanh, store
#pragma unroll
    for (int i = 0; i < 8; ++i) {
        const int m = m0 + ty * 8 + i;
        if (TRANSP) {
            // acc[i][j] is element o = d*128 + e, d = bd*16+tx, e = be*8+j.
            // d-interleaved store: C[m][((d>>2)*128 + e)*4 + (d&3)]
            const int d = bd * 16 + tx;
#pragma unroll
            for (int j = 0; j < 8; ++j) {
                const int ee = be * 8 + j;
                const int o = d * 128 + ee;
                const float v = __fadd_rn(acc[i][j], bias[o]);
                C[(size_t)m * N + ((size_t)(d >> 2) * 128 + ee) * 4 + (d & 3)] = v;
            }
        } else {
            float v[8];
#pragma unroll
            for (int j = 0; j < 8; ++j) {
                const int n = n0 + tx * 8 + j;
                v[j] = __fadd_rn(acc[i][j], bias[n]);
                if (ACT) v[j] = xla_tanhf(v[j]);
            }
            float4* dst = (float4*)(C + (size_t)m * N + (n0 + tx * 8));
            dst[0] = make_float4(v[0], v[1], v[2], v[3]);
            dst[1] = make_float4(v[4], v[5], v[6], v[7]);
        }
    }
}

// ---------------------------------------------------------------------------
// Sequential attractor scan — r20: prefetch distance EIGHT quarters (TWO full
// steps), 8 named buffers w0..w7 (256 VGPRs), period-2 rotation implemented
// by unrolling the loop over a step-PAIR so every buffer index is static
// (rule #20). Standalone scan runs 128 thr / 1 block/CU -> 1 wave/SIMD ->
// the full 512-VGPR budget is available; ~290 VGPRs, no occupancy change.
// Rationale: r16's distance-4 (one step) exposes HBM latency (~900-1000 cyc)
// every step -> measured ~2250 cyc/step vs the 512-cyc serial-add-chain
// floor. Distance-8 keeps ~56 loads in flight (vmcnt cap 63) ~= 1.75 steps
// of cover.
// Chain is op-for-op the verified sequence: ONE accumulator, strictly
// ascending d (q asc, dq asc, x,y,z,w = d..d+3), non-fused rn ops — bitwise
// contract. Prefetch is consume-then-refill with a monotone cursor (no
// clamp): overrun <= 8 quarters = 128 KB, Wa buffers padded by 160 KB.
// ---------------------------------------------------------------------------
#define SCAN_CONSUME(Q, BUF)                                                \
    {                                                                       \
        /* consume quarter Q: d = 32Q .. 32Q+31, strictly ascending */      \
        _Pragma("unroll")                                                   \
        for (int dq = 0; dq < 8; ++dq) {                                    \
            const float4 t4 = *(const float4*)&et[s][(Q) * 32 + dq * 4];    \
            const float4 wv = BUF[dq]; /* W[d..d+3][e], d = 32Q+4dq */      \
            sum = __fadd_rn(sum, __fmul_rn(t4.x, wv.x));                    \
            sum = __fadd_rn(sum, __fmul_rn(t4.y, wv.y));                    \
            sum = __fadd_rn(sum, __fmul_rn(t4.z, wv.z));                    \
            sum = __fadd_rn(sum, __fmul_rn(t4.w, wv.w));                    \
        }                                                                   \
    }

#define SCAN_REFILL(BUF)                                                    \
    {                                                                       \
        /* refill BUF with the quarter 8 ahead (straight-line, no clamp) */ \
        _Pragma("unroll")                                                   \
        for (int u = 0; u < 8; ++u) BUF[u] = Pf[u * 128];                   \
        Pf += 1024;                                                         \
        asm volatile("" ::: "memory");                                      \
    }

#define SCAN_STEP(B0, B1, B2, B3)                                           \
    {                                                                       \
        float sum = 0.f; /* ONE accumulator, ascending d across quarters */ \
        SCAN_CONSUME(0, B0) SCAN_REFILL(B0)                                 \
        SCAN_CONSUME(1, B1) SCAN_REFILL(B1)                                 \
        SCAN_CONSUME(2, B2) SCAN_REFILL(B2)                                 \
        SCAN_CONSUME(3, B3) SCAN_REFILL(B3)                                 \
        const float v = fminf(fmaxf(sum, -5.f), 5.f); /* jnp.clip */        \
        out[((size_t)b * SS + (i0 + ii)) * ENC + e] = v;                    \
        et[s ^ 1][e] = v;                                                   \
        __syncthreads(); /* publishes et[s^1]; orders next overwrite */     \
        s ^= 1;                                                             \
        ++ii;                                                               \
    }

__global__ __launch_bounds__(128, 1) void scan_kernel(const float* __restrict__ Wa,
                                                      const float* __restrict__ e0,
                                                      float* __restrict__ et_state,
                                                      float* __restrict__ out,
                                                      int i0, int CH) {
    __shared__ float et[2][128];
    const int b = blockIdx.x;
    const int e = threadIdx.x;  // 0..127

    int s = 0;
    if (i0 == 0) {
        const float v = e0[e];
        et[0][e] = v;
        out[(size_t)b * SS * ENC + e] = v;
    } else {
        et[0][e] = et_state[b * 128 + e];
    }
    __syncthreads();

    const int start = (i0 == 0) ? 1 : 0;
    const float4* Wb4 = (const float4*)(Wa + (size_t)b * CH * (ENC * ENC));
    // step stride in float4: ENC*ENC/4 = 4096; quarter stride: 8*128 = 1024

    // 8 quarter buffers x 8 float4 = 256 VGPRs; preload quarters 0..7 =
    // steps `start` and `start+1` (two full steps in flight).
    float4 w0[8], w1[8], w2[8], w3[8], w4[8], w5[8], w6[8], w7[8];
    const float4* Pq = Wb4 + (size_t)start * 4096 + e;
#pragma unroll
    for (int u = 0; u < 8; ++u) w0[u] = Pq[u * 128];
#pragma unroll
    for (int u = 0; u < 8; ++u) w1[u] = Pq[(8 + u) * 128];
#pragma unroll
    for (int u = 0; u < 8; ++u) w2[u] = Pq[(16 + u) * 128];
#pragma unroll
    for (int u = 0; u < 8; ++u) w3[u] = Pq[(24 + u) * 128];
#pragma unroll
    for (int u = 0; u < 8; ++u) w4[u] = Pq[(32 + u) * 128];
#pragma unroll
    for (int u = 0; u < 8; ++u) w5[u] = Pq[(40 + u) * 128];
#pragma unroll
    for (int u = 0; u < 8; ++u) w6[u] = Pq[(48 + u) * 128];
#pragma unroll
    for (int u = 0; u < 8; ++u) w7[u] = Pq[(56 + u) * 128];
    const float4* Pf = Pq + 8192;   // prefetch cursor: quarter 8
    asm volatile("" ::: "memory");  // loads pinned before first chain

    int ii = start;
    const int pairs = (CH - start) >> 1;
    const int odd = (CH - start) & 1;

    for (int p = 0; p < pairs; ++p) {
        // even step (ii-start even): buffer set 0; refills land 2 steps ahead
        SCAN_STEP(w0, w1, w2, w3)
        // odd step: buffer set 1
        SCAN_STEP(w4, w5, w6, w7)
    }
    if (odd) {
        // leftover step ((ii-start) even -> set 0), consume-only (no refill)
        float sum = 0.f;
        SCAN_CONSUME(0, w0)
        SCAN_CONSUME(1, w1)
        SCAN_CONSUME(2, w2)
        SCAN_CONSUME(3, w3)
        const float v = fminf(fmaxf(sum, -5.f), 5.f);
        out[((size_t)b * SS + (i0 + ii)) * ENC + e] = v;
        et[s ^ 1][e] = v;
        __syncthreads();
        s ^= 1;
    }
    et_state[b * 128 + e] = et[s][e];
}

// ---------------------------------------------------------------------------
extern "C" void kernel_launch(void* const* d_in, const int* in_sizes, int n_in,
                              void* d_out, int out_size, void* d_ws, size_t ws_size,
                              hipStream_t stream) {
    const float* A  = (const float*)d_in[0];  // (B,S,E)   = (8,512,128) fp32
    const float* W1 = (const float*)d_in[1];  // (H,E)     = (512,128)  fp32
    const float* b1 = (const float*)d_in[2];  // (H,)      fp32
    const float* W2 = (const float*)d_in[3];  // (ENC*ENC,H) = (16384,512) fp32
    const float* b2 = (const float*)d_in[4];  // (ENC*ENC,) fp32
    const float* e0 = (const float*)d_in[5];  // (1,ENC)   fp32
    float* out = (float*)d_out;               // (B,S,ENC) fp32

    // Serial r16 schedule (known-good base), scan pad 160 KB for the
    // unclamped 8-quarter prefetch overrun.
    // Pick the largest chunk CH (steps) whose fp32 workspace fits ws_size.
    // ws layout: [et_state 4KB][hidden_c Mc*512 f32][Wa_c Mc*16384 f32 + pad]
    const size_t WA_PAD = 163840;  // 160 KB
    int CH = 16;
    for (int c = 512; c >= 16; c >>= 1) {
        const size_t Mc = (size_t)BB * c;
        const size_t need = 4096 + Mc * HH * sizeof(float) +
                            Mc * (size_t)(ENC * ENC) * sizeof(float) + WA_PAD;
        if (need <= ws_size) { CH = c; break; }
    }
    const int Mc = BB * CH;
    int chsh = 0;
    while ((1 << chsh) < CH) ++chsh;
    const int chm1 = CH - 1;

    float* et_state = (float*)d_ws;
    float* hidden   = (float*)((char*)d_ws + 4096);
    float* Wa       = hidden + (size_t)Mc * HH;   // d-interleaved layout (Wa4)

    for (int i0 = 0; i0 < SS; i0 += CH) {
        // GEMM1: hidden_c = tanh(A[chunk rows] @ W1^T + b1)  [Mc x 512, K=128]
        dim3 g1(HH / 128, Mc / 128);
        gemm_nt<1, 1, 0><<<g1, 256, 0, stream>>>(A, W1, b1, hidden, HH, EE,
                                                 chm1, chsh, i0);
        // GEMM2: Wa4_c = (hidden_c @ W2^T + b2) stored d-interleaved
        dim3 g2((ENC * ENC) / 128, Mc / 128);
        gemm_nt<0, 0, 1><<<g2, 256, 0, stream>>>(hidden, W2, b2, Wa, ENC * ENC,
                                                 HH, 0, 0, 0);
        // scan this chunk (one workgroup per batch; fp32 state in ws)
        scan_kernel<<<BB, 128, 0, stream>>>(Wa, e0, et_state, out, i0, CH);
    }
}

// Round 5
// 1559.686 us; speedup vs baseline: 1.3083x; 1.0629x over previous
//
#include <hip/hip_runtime.h>
#include <cstddef>

// Problem constants (reference: B=8, S=512, E=128, H=512, ENC=128)
#define BB 8
#define SS 512
#define EE 128
#define HH 512
#define ENC 128

// ---------------------------------------------------------------------------
// Bit-exact emulation of XLA CPU's EmitTanh (verified bitwise r6..r15).
// All ops rn, NON-fused. __f*_rn intrinsics block compiler contraction.
// NOTE (r8): packed v_pk_* fp32 is NOT bit-identical on gfx950 — scalar only.
// ---------------------------------------------------------------------------
__device__ __forceinline__ float xla_tanhf(float x) {
    const float cx = fminf(fmaxf(x, -9.0f), 9.0f);
    const float x2 = __fmul_rn(cx, cx);
    float p = -2.76076847742355e-16f;
    p = __fadd_rn(__fmul_rn(p, x2), 2.00018790482477e-13f);
    p = __fadd_rn(__fmul_rn(p, x2), -8.60467152213735e-11f);
    p = __fadd_rn(__fmul_rn(p, x2), 5.12229709037114e-08f);
    p = __fadd_rn(__fmul_rn(p, x2), 1.48572235717979e-05f);
    p = __fadd_rn(__fmul_rn(p, x2), 6.37261928875436e-04f);
    p = __fadd_rn(__fmul_rn(p, x2), 4.89352455891786e-03f);
    const float num = __fmul_rn(cx, p);
    float q = 1.19825839466702e-06f;
    q = __fadd_rn(__fmul_rn(q, x2), 1.18534705686654e-04f);
    q = __fadd_rn(__fmul_rn(q, x2), 2.26843463243900e-03f);
    q = __fadd_rn(__fmul_rn(q, x2), 4.89352518554385e-03f);
    const float r = __fdiv_rn(num, q);
    return (fabsf(x) < 0.0004f) ? x : r;
}

// Map a packed chunk-row m -> global action row:
//   b = m >> chsh (CH = chm1+1), global row = b*SS + i0 + (m & chm1)
__device__ __forceinline__ int arow_map(int m, int chm1, int chsh, int i0) {
    return ((m >> chsh) * SS) + i0 + (m & chm1);
}

// ---------------------------------------------------------------------------
// Tiled GEMM, bitwise-preserving XLA-CPU dot semantics (VERIFIED r6..r20 —
// scalar v_mul/v_add only). GEMM2 measured at 95% of its scalar-VALU floor
// (~457 us/chunk @CH=256). K-chain: one accumulator per element, k0 tiles
// ascend, inner k ascends — DO NOT TOUCH.
//
// TRANSP=1 (GEMM2 only): block bx covers B-rows o = d*128+e with
// d in [16*bd,16*bd+16), e in [8*be,8*be+8)  (bd=bx>>4, be=bx&15).
// Epilogue stores the d-INTERLEAVED layout:
//   Wa4[m][(d>>2)*128 + e] as float4 component (d&3)
// so the scan's quarter loads are lane-consecutive float4 (r15-proven).
// Values bit-identical; address-only.
// ---------------------------------------------------------------------------
template <int ACT, int MAPROW, int TRANSP>
__global__ __launch_bounds__(256) void gemm_nt(const float* __restrict__ A,
                                               const float* __restrict__ Bm,
                                               const float* __restrict__ bias,
                                               float* __restrict__ C,
                                               int N, int K,
                                               int chm1, int chsh, int i0) {
    __shared__ float As[16][128];
    __shared__ float Bs[16][128];

    const int tid = threadIdx.x;
    const int tx = tid & 15;   // n-direction (8 cols each)
    const int ty = tid >> 4;   // m-direction (8 rows each)
    const int n0 = blockIdx.x * 128;
    const int m0 = blockIdx.y * 128;
    const int bd = blockIdx.x >> 4;   // TRANSP: d-tile (0..7)
    const int be = blockIdx.x & 15;   // TRANSP: e-tile (0..15)

    const int lr = tid >> 2;          // 0..63 (row within tile)
    const int lc = (tid & 3) << 2;    // 0,4,8,12 (col within K-tile)

    const int ga0 = MAPROW ? arow_map(m0 + lr, chm1, chsh, i0) : (m0 + lr);
    const int ga1 = MAPROW ? arow_map(m0 + lr + 64, chm1, chsh, i0) : (m0 + lr + 64);

    // B-row indices for the two loader rows (identity unless TRANSP)
    const int r0 = lr, r1 = lr + 64;
    const int gb0 = TRANSP ? ((bd * 16 + (r0 >> 3)) * 128 + be * 8 + (r0 & 7))
                           : (n0 + r0);
    const int gb1 = TRANSP ? ((bd * 16 + (r1 >> 3)) * 128 + be * 8 + (r1 & 7))
                           : (n0 + r1);

    float acc[8][8];
#pragma unroll
    for (int i = 0; i < 8; ++i)
#pragma unroll
        for (int j = 0; j < 8; ++j) acc[i][j] = 0.f;

    for (int k0 = 0; k0 < K; k0 += 16) {
        const float4 a0 = *(const float4*)(A + (size_t)ga0 * K + (k0 + lc));
        const float4 a1 = *(const float4*)(A + (size_t)ga1 * K + (k0 + lc));
        const float4 b0 = *(const float4*)(Bm + (size_t)gb0 * K + (k0 + lc));
        const float4 b1 = *(const float4*)(Bm + (size_t)gb1 * K + (k0 + lc));

        __syncthreads();  // previous iteration's compute done before overwrite

        As[lc + 0][lr] = a0.x; As[lc + 1][lr] = a0.y;
        As[lc + 2][lr] = a0.z; As[lc + 3][lr] = a0.w;
        As[lc + 0][lr + 64] = a1.x; As[lc + 1][lr + 64] = a1.y;
        As[lc + 2][lr + 64] = a1.z; As[lc + 3][lr + 64] = a1.w;
        Bs[lc + 0][lr] = b0.x; Bs[lc + 1][lr] = b0.y;
        Bs[lc + 2][lr] = b0.z; Bs[lc + 3][lr] = b0.w;
        Bs[lc + 0][lr + 64] = b1.x; Bs[lc + 1][lr + 64] = b1.y;
        Bs[lc + 2][lr + 64] = b1.z; Bs[lc + 3][lr + 64] = b1.w;

        __syncthreads();

#pragma unroll
        for (int k = 0; k < 16; ++k) {   // ascending k within tile
            const float4 av0 = *(const float4*)&As[k][ty * 8];
            const float4 av1 = *(const float4*)&As[k][ty * 8 + 4];
            const float4 bv0 = *(const float4*)&Bs[k][tx * 8];
            const float4 bv1 = *(const float4*)&Bs[k][tx * 8 + 4];
            const float a[8] = {av0.x, av0.y, av0.z, av0.w, av1.x, av1.y, av1.z, av1.w};
            const float b[8] = {bv0.x, bv0.y, bv0.z, bv0.w, bv1.x, bv1.y, bv1.z, bv1.w};
#pragma unroll
            for (int i = 0; i < 8; ++i)
#pragma unroll
                for (int j = 0; j < 8; ++j)
                    acc[i][j] = __fadd_rn(acc[i][j], __fmul_rn(a[i], b[j]));
        }
    }

    // epilogue: + bias (after full k-chain), optional XLA tanh, store
#pragma unroll
    for (int i = 0; i < 8; ++i) {
        const int m = m0 + ty * 8 + i;
        if (TRANSP) {
            // acc[i][j] is element o = d*128 + e, d = bd*16+tx, e = be*8+j.
            // d-interleaved store: C[m][((d>>2)*128 + e)*4 + (d&3)]
            const int d = bd * 16 + tx;
#pragma unroll
            for (int j = 0; j < 8; ++j) {
                const int ee = be * 8 + j;
                const int o = d * 128 + ee;
                const float v = __fadd_rn(acc[i][j], bias[o]);
                C[(size_t)m * N + ((size_t)(d >> 2) * 128 + ee) * 4 + (d & 3)] = v;
            }
        } else {
            float v[8];
#pragma unroll
            for (int j = 0; j < 8; ++j) {
                const int n = n0 + tx * 8 + j;
                v[j] = __fadd_rn(acc[i][j], bias[n]);
                if (ACT) v[j] = xla_tanhf(v[j]);
            }
            float4* dst = (float4*)(C + (size_t)m * N + (n0 + tx * 8));
            dst[0] = make_float4(v[0], v[1], v[2], v[3]);
            dst[1] = make_float4(v[4], v[5], v[6], v[7]);
        }
    }
}

// ---------------------------------------------------------------------------
// r21: non-draining workgroup barrier for the scan.
// __syncthreads() emits `s_waitcnt vmcnt(0) lgkmcnt(0)` before s_barrier
// (workgroup fence semantics) — which drains the ENTIRE prefetch queue every
// step, re-exposing ~900 cyc of load latency per step regardless of prefetch
// distance (this is why r16 measured ~2250 cyc/step and why r20's deeper
// pipeline regressed: more bytes to drain). The scan's ping-pong only needs
// LDS ordering across the block's 2 waves:
//     ds_write et  ->  s_waitcnt lgkmcnt(0)  ->  s_barrier
// Global prefetch loads target VGPRs and are already guarded by the
// compiler's precise vmcnt(N) waits at their consume sites (r16-proven).
// Memory-clobber asm on BOTH sides of the raw barrier pins all memory ops
// at IR level (the m201-verified sandwich pattern).
// ---------------------------------------------------------------------------
__device__ __forceinline__ void scan_barrier_nodrain() {
    asm volatile("s_waitcnt lgkmcnt(0)" ::: "memory");
    __builtin_amdgcn_s_barrier();
    asm volatile("" ::: "memory");
}

// ---------------------------------------------------------------------------
// Sequential attractor scan — r20 structure (distance EIGHT quarters = TWO
// full steps, 8 named buffers w0..w7 ~ 256 VGPRs, period-2 rotation via
// step-pair unrolling, all indices static per rule #20) + r21's non-draining
// barrier. Standalone kernel: 128 thr / 1 block/CU -> full 512-VGPR budget.
// Chain is op-for-op the verified sequence: ONE accumulator, strictly
// ascending d (q asc, dq asc, x,y,z,w = d..d+3), non-fused rn ops — bitwise
// contract. Prefetch is consume-then-refill with a monotone cursor (no
// clamp): overrun <= 8 quarters = 128 KB, Wa buffers padded by 160 KB.
// ---------------------------------------------------------------------------
#define SCAN_CONSUME(Q, BUF)                                                \
    {                                                                       \
        /* consume quarter Q: d = 32Q .. 32Q+31, strictly ascending */      \
        _Pragma("unroll")                                                   \
        for (int dq = 0; dq < 8; ++dq) {                                    \
            const float4 t4 = *(const float4*)&et[s][(Q) * 32 + dq * 4];    \
            const float4 wv = BUF[dq]; /* W[d..d+3][e], d = 32Q+4dq */      \
            sum = __fadd_rn(sum, __fmul_rn(t4.x, wv.x));                    \
            sum = __fadd_rn(sum, __fmul_rn(t4.y, wv.y));                    \
            sum = __fadd_rn(sum, __fmul_rn(t4.z, wv.z));                    \
            sum = __fadd_rn(sum, __fmul_rn(t4.w, wv.w));                    \
        }                                                                   \
    }

#define SCAN_REFILL(BUF)                                                    \
    {                                                                       \
        /* refill BUF with the quarter 8 ahead (straight-line, no clamp) */ \
        _Pragma("unroll")                                                   \
        for (int u = 0; u < 8; ++u) BUF[u] = Pf[u * 128];                   \
        Pf += 1024;                                                         \
        asm volatile("" ::: "memory");                                      \
    }

#define SCAN_STEP(B0, B1, B2, B3)                                           \
    {                                                                       \
        float sum = 0.f; /* ONE accumulator, ascending d across quarters */ \
        SCAN_CONSUME(0, B0) SCAN_REFILL(B0)                                 \
        SCAN_CONSUME(1, B1) SCAN_REFILL(B1)                                 \
        SCAN_CONSUME(2, B2) SCAN_REFILL(B2)                                 \
        SCAN_CONSUME(3, B3) SCAN_REFILL(B3)                                 \
        const float v = fminf(fmaxf(sum, -5.f), 5.f); /* jnp.clip */        \
        out[((size_t)b * SS + (i0 + ii)) * ENC + e] = v;                    \
        et[s ^ 1][e] = v;                                                   \
        scan_barrier_nodrain(); /* publishes et[s^1]; keeps vmcnt queue */  \
        s ^= 1;                                                             \
        ++ii;                                                               \
    }

__global__ __launch_bounds__(128, 1) void scan_kernel(const float* __restrict__ Wa,
                                                      const float* __restrict__ e0,
                                                      float* __restrict__ et_state,
                                                      float* __restrict__ out,
                                                      int i0, int CH) {
    __shared__ float et[2][128];
    const int b = blockIdx.x;
    const int e = threadIdx.x;  // 0..127

    int s = 0;
    if (i0 == 0) {
        const float v = e0[e];
        et[0][e] = v;
        out[(size_t)b * SS * ENC + e] = v;
    } else {
        et[0][e] = et_state[b * 128 + e];
    }
    __syncthreads();   // once, before the pipeline — drain is harmless here

    const int start = (i0 == 0) ? 1 : 0;
    const float4* Wb4 = (const float4*)(Wa + (size_t)b * CH * (ENC * ENC));
    // step stride in float4: ENC*ENC/4 = 4096; quarter stride: 8*128 = 1024

    // 8 quarter buffers x 8 float4 = 256 VGPRs; preload quarters 0..7 =
    // steps `start` and `start+1` (two full steps in flight).
    float4 w0[8], w1[8], w2[8], w3[8], w4[8], w5[8], w6[8], w7[8];
    const float4* Pq = Wb4 + (size_t)start * 4096 + e;
#pragma unroll
    for (int u = 0; u < 8; ++u) w0[u] = Pq[u * 128];
#pragma unroll
    for (int u = 0; u < 8; ++u) w1[u] = Pq[(8 + u) * 128];
#pragma unroll
    for (int u = 0; u < 8; ++u) w2[u] = Pq[(16 + u) * 128];
#pragma unroll
    for (int u = 0; u < 8; ++u) w3[u] = Pq[(24 + u) * 128];
#pragma unroll
    for (int u = 0; u < 8; ++u) w4[u] = Pq[(32 + u) * 128];
#pragma unroll
    for (int u = 0; u < 8; ++u) w5[u] = Pq[(40 + u) * 128];
#pragma unroll
    for (int u = 0; u < 8; ++u) w6[u] = Pq[(48 + u) * 128];
#pragma unroll
    for (int u = 0; u < 8; ++u) w7[u] = Pq[(56 + u) * 128];
    const float4* Pf = Pq + 8192;   // prefetch cursor: quarter 8
    asm volatile("" ::: "memory");  // loads pinned before first chain

    int ii = start;
    const int pairs = (CH - start) >> 1;
    const int odd = (CH - start) & 1;

    for (int p = 0; p < pairs; ++p) {
        // even step (ii-start even): buffer set 0; refills land 2 steps ahead
        SCAN_STEP(w0, w1, w2, w3)
        // odd step: buffer set 1
        SCAN_STEP(w4, w5, w6, w7)
    }
    if (odd) {
        // leftover step ((ii-start) even -> set 0), consume-only (no refill)
        float sum = 0.f;
        SCAN_CONSUME(0, w0)
        SCAN_CONSUME(1, w1)
        SCAN_CONSUME(2, w2)
        SCAN_CONSUME(3, w3)
        const float v = fminf(fmaxf(sum, -5.f), 5.f);
        out[((size_t)b * SS + (i0 + ii)) * ENC + e] = v;
        et[s ^ 1][e] = v;
        scan_barrier_nodrain();
        s ^= 1;
    }
    et_state[b * 128 + e] = et[s][e];
}

// ---------------------------------------------------------------------------
extern "C" void kernel_launch(void* const* d_in, const int* in_sizes, int n_in,
                              void* d_out, int out_size, void* d_ws, size_t ws_size,
                              hipStream_t stream) {
    const float* A  = (const float*)d_in[0];  // (B,S,E)   = (8,512,128) fp32
    const float* W1 = (const float*)d_in[1];  // (H,E)     = (512,128)  fp32
    const float* b1 = (const float*)d_in[2];  // (H,)      fp32
    const float* W2 = (const float*)d_in[3];  // (ENC*ENC,H) = (16384,512) fp32
    const float* b2 = (const float*)d_in[4];  // (ENC*ENC,) fp32
    const float* e0 = (const float*)d_in[5];  // (1,ENC)   fp32
    float* out = (float*)d_out;               // (B,S,ENC) fp32

    // Serial r16 schedule (known-good base), scan pad 160 KB for the
    // unclamped 8-quarter prefetch overrun.
    // Pick the largest chunk CH (steps) whose fp32 workspace fits ws_size.
    // ws layout: [et_state 4KB][hidden_c Mc*512 f32][Wa_c Mc*16384 f32 + pad]
    const size_t WA_PAD = 163840;  // 160 KB
    int CH = 16;
    for (int c = 512; c >= 16; c >>= 1) {
        const size_t Mc = (size_t)BB * c;
        const size_t need = 4096 + Mc * HH * sizeof(float) +
                            Mc * (size_t)(ENC * ENC) * sizeof(float) + WA_PAD;
        if (need <= ws_size) { CH = c; break; }
    }
    const int Mc = BB * CH;
    int chsh = 0;
    while ((1 << chsh) < CH) ++chsh;
    const int chm1 = CH - 1;

    float* et_state = (float*)d_ws;
    float* hidden   = (float*)((char*)d_ws + 4096);
    float* Wa       = hidden + (size_t)Mc * HH;   // d-interleaved layout (Wa4)

    for (int i0 = 0; i0 < SS; i0 += CH) {
        // GEMM1: hidden_c = tanh(A[chunk rows] @ W1^T + b1)  [Mc x 512, K=128]
        dim3 g1(HH / 128, Mc / 128);
        gemm_nt<1, 1, 0><<<g1, 256, 0, stream>>>(A, W1, b1, hidden, HH, EE,
                                                 chm1, chsh, i0);
        // GEMM2: Wa4_c = (hidden_c @ W2^T + b2) stored d-interleaved
        dim3 g2((ENC * ENC) / 128, Mc / 128);
        gemm_nt<0, 0, 1><<<g2, 256, 0, stream>>>(hidden, W2, b2, Wa, ENC * ENC,
                                                 HH, 0, 0, 0);
        // scan this chunk (one workgroup per batch; fp32 state in ws)
        scan_kernel<<<BB, 128, 0, stream>>>(Wa, e0, et_state, out, i0, CH);
    }
}

// Round 6
// 1394.127 us; speedup vs baseline: 1.4636x; 1.1188x over previous
//
#include <hip/hip_runtime.h>
#include <cstddef>

// Problem constants (reference: B=8, S=512, E=128, H=512, ENC=128)
#define BB 8
#define SS 512
#define EE 128
#define HH 512
#define ENC 128

// ---------------------------------------------------------------------------
// Bit-exact emulation of XLA CPU's EmitTanh (verified bitwise r6..r15).
// All ops rn, NON-fused. __f*_rn intrinsics block compiler contraction.
// NOTE (r8): packed v_pk_* fp32 is NOT bit-identical on gfx950 — scalar only.
// ---------------------------------------------------------------------------
__device__ __forceinline__ float xla_tanhf(float x) {
    const float cx = fminf(fmaxf(x, -9.0f), 9.0f);
    const float x2 = __fmul_rn(cx, cx);
    float p = -2.76076847742355e-16f;
    p = __fadd_rn(__fmul_rn(p, x2), 2.00018790482477e-13f);
    p = __fadd_rn(__fmul_rn(p, x2), -8.60467152213735e-11f);
    p = __fadd_rn(__fmul_rn(p, x2), 5.12229709037114e-08f);
    p = __fadd_rn(__fmul_rn(p, x2), 1.48572235717979e-05f);
    p = __fadd_rn(__fmul_rn(p, x2), 6.37261928875436e-04f);
    p = __fadd_rn(__fmul_rn(p, x2), 4.89352455891786e-03f);
    const float num = __fmul_rn(cx, p);
    float q = 1.19825839466702e-06f;
    q = __fadd_rn(__fmul_rn(q, x2), 1.18534705686654e-04f);
    q = __fadd_rn(__fmul_rn(q, x2), 2.26843463243900e-03f);
    q = __fadd_rn(__fmul_rn(q, x2), 4.89352518554385e-03f);
    const float r = __fdiv_rn(num, q);
    return (fabsf(x) < 0.0004f) ? x : r;
}

// Map a packed chunk-row m -> global action row:
//   b = m >> chsh (CH = chm1+1), global row = b*SS + i0 + (m & chm1)
__device__ __forceinline__ int arow_map(int m, int chm1, int chsh, int i0) {
    return ((m >> chsh) * SS) + i0 + (m & chm1);
}

// ---------------------------------------------------------------------------
// Tiled GEMM, bitwise-preserving XLA-CPU dot semantics (VERIFIED r6..r21 —
// scalar v_mul/v_add only). K-chain: one accumulator per element, k0 tiles
// ascend, inner k ascends — DO NOT TOUCH.
//
// r22 — LDS bank-conflict elimination (address-only; measured 5.87e7 extra
// cycles/dispatch = ~21% of GEMM2 time at r21):
//   * LDS rows padded 128 -> 132 floats: write pattern [lc+i][lr] goes
//     4-way -> 2-way (2-way is free, m136). 132%4==0 keeps float4 align.
//   * b-columns remapped from blocked (tx*8+j) to STRIDED float4s:
//     thread (tx) reads Bs[k][tx*4] and Bs[k][64+tx*4] — 16 lanes span 64
//     consecutive floats -> 2 addresses/bank-quad (broadcast over ty) ->
//     2-way free, was 4-way (tx=0,4,8,12 all hit bank 0 with 128-blocked).
//     Each (m,n) dot product is computed by exactly one thread with the
//     UNCHANGED k-chain; only the thread<->n ownership moves. Epilogue
//     bias/store indices remapped to match: j<4 -> c=tx*4+j,
//     j>=4 -> c=64+tx*4+(j-4); n = n0+c (plain) / o-decode via c (TRANSP).
//
// TRANSP=1 (GEMM2 only): block bx covers B-rows o = d*128+e with
// d in [16*bd,16*bd+16), e in [8*be,8*be+8)  (bd=bx>>4, be=bx&15).
// Epilogue stores the d-INTERLEAVED layout:
//   Wa4[m][(d>>2)*128 + e] as float4 component (d&3)
// so the scan's quarter loads are lane-consecutive float4 (r15-proven).
// ---------------------------------------------------------------------------
template <int ACT, int MAPROW, int TRANSP>
__global__ __launch_bounds__(256) void gemm_nt(const float* __restrict__ A,
                                               const float* __restrict__ Bm,
                                               const float* __restrict__ bias,
                                               float* __restrict__ C,
                                               int N, int K,
                                               int chm1, int chsh, int i0) {
    __shared__ float As[16][132];   // +4 pad: kills 4-way write conflicts
    __shared__ float Bs[16][132];

    const int tid = threadIdx.x;
    const int tx = tid & 15;   // n-direction (8 cols each, strided mapping)
    const int ty = tid >> 4;   // m-direction (8 rows each)
    const int n0 = blockIdx.x * 128;
    const int m0 = blockIdx.y * 128;
    const int bd = blockIdx.x >> 4;   // TRANSP: d-tile (0..7)
    const int be = blockIdx.x & 15;   // TRANSP: e-tile (0..15)

    const int lr = tid >> 2;          // 0..63 (row within tile)
    const int lc = (tid & 3) << 2;    // 0,4,8,12 (col within K-tile)

    const int ga0 = MAPROW ? arow_map(m0 + lr, chm1, chsh, i0) : (m0 + lr);
    const int ga1 = MAPROW ? arow_map(m0 + lr + 64, chm1, chsh, i0) : (m0 + lr + 64);

    // B-row indices for the two loader rows (identity unless TRANSP)
    const int r0 = lr, r1 = lr + 64;
    const int gb0 = TRANSP ? ((bd * 16 + (r0 >> 3)) * 128 + be * 8 + (r0 & 7))
                           : (n0 + r0);
    const int gb1 = TRANSP ? ((bd * 16 + (r1 >> 3)) * 128 + be * 8 + (r1 & 7))
                           : (n0 + r1);

    float acc[8][8];
#pragma unroll
    for (int i = 0; i < 8; ++i)
#pragma unroll
        for (int j = 0; j < 8; ++j) acc[i][j] = 0.f;

    for (int k0 = 0; k0 < K; k0 += 16) {
        const float4 a0 = *(const float4*)(A + (size_t)ga0 * K + (k0 + lc));
        const float4 a1 = *(const float4*)(A + (size_t)ga1 * K + (k0 + lc));
        const float4 b0 = *(const float4*)(Bm + (size_t)gb0 * K + (k0 + lc));
        const float4 b1 = *(const float4*)(Bm + (size_t)gb1 * K + (k0 + lc));

        __syncthreads();  // previous iteration's compute done before overwrite

        As[lc + 0][lr] = a0.x; As[lc + 1][lr] = a0.y;
        As[lc + 2][lr] = a0.z; As[lc + 3][lr] = a0.w;
        As[lc + 0][lr + 64] = a1.x; As[lc + 1][lr + 64] = a1.y;
        As[lc + 2][lr + 64] = a1.z; As[lc + 3][lr + 64] = a1.w;
        Bs[lc + 0][lr] = b0.x; Bs[lc + 1][lr] = b0.y;
        Bs[lc + 2][lr] = b0.z; Bs[lc + 3][lr] = b0.w;
        Bs[lc + 0][lr + 64] = b1.x; Bs[lc + 1][lr + 64] = b1.y;
        Bs[lc + 2][lr + 64] = b1.z; Bs[lc + 3][lr + 64] = b1.w;

        __syncthreads();

#pragma unroll
        for (int k = 0; k < 16; ++k) {   // ascending k within tile
            const float4 av0 = *(const float4*)&As[k][ty * 8];
            const float4 av1 = *(const float4*)&As[k][ty * 8 + 4];
            const float4 bv0 = *(const float4*)&Bs[k][tx * 4];        // strided
            const float4 bv1 = *(const float4*)&Bs[k][64 + tx * 4];   // strided
            const float a[8] = {av0.x, av0.y, av0.z, av0.w, av1.x, av1.y, av1.z, av1.w};
            const float b[8] = {bv0.x, bv0.y, bv0.z, bv0.w, bv1.x, bv1.y, bv1.z, bv1.w};
#pragma unroll
            for (int i = 0; i < 8; ++i)
#pragma unroll
                for (int j = 0; j < 8; ++j)
                    acc[i][j] = __fadd_rn(acc[i][j], __fmul_rn(a[i], b[j]));
        }
    }

    // epilogue: + bias (after full k-chain), optional XLA tanh, store.
    // acc[i][j] is output col c = (j<4) ? tx*4+j : 64+tx*4+(j-4) of the tile.
#pragma unroll
    for (int i = 0; i < 8; ++i) {
        const int m = m0 + ty * 8 + i;
        if (TRANSP) {
            // in-tile col c -> o = d*128+ee, d = bd*16+(c>>3), ee = be*8+(c&7)
            // d-interleaved store: C[m][((d>>2)*128 + ee)*4 + (d&3)]
#pragma unroll
            for (int j = 0; j < 8; ++j) {
                const int c = (j < 4) ? (tx * 4 + j) : (64 + tx * 4 + (j - 4));
                const int d = bd * 16 + (c >> 3);
                const int ee = be * 8 + (c & 7);
                const int o = d * 128 + ee;
                const float v = __fadd_rn(acc[i][j], bias[o]);
                C[(size_t)m * N + ((size_t)(d >> 2) * 128 + ee) * 4 + (d & 3)] = v;
            }
        } else {
            float v[8];
#pragma unroll
            for (int j = 0; j < 4; ++j) {
                const int n = n0 + tx * 4 + j;
                v[j] = __fadd_rn(acc[i][j], bias[n]);
                if (ACT) v[j] = xla_tanhf(v[j]);
            }
#pragma unroll
            for (int j = 4; j < 8; ++j) {
                const int n = n0 + 64 + tx * 4 + (j - 4);
                v[j] = __fadd_rn(acc[i][j], bias[n]);
                if (ACT) v[j] = xla_tanhf(v[j]);
            }
            *(float4*)(C + (size_t)m * N + (n0 + tx * 4)) =
                make_float4(v[0], v[1], v[2], v[3]);
            *(float4*)(C + (size_t)m * N + (n0 + 64 + tx * 4)) =
                make_float4(v[4], v[5], v[6], v[7]);
        }
    }
}

// ---------------------------------------------------------------------------
// r21-proven non-draining workgroup barrier (validated correct, absmax 0.0):
// __syncthreads() emits `s_waitcnt vmcnt(0) lgkmcnt(0)` before s_barrier,
// draining the whole prefetch queue each step and re-exposing ~900 cyc of
// load latency per step. The scan's ping-pong only needs LDS ordering:
//     ds_write et -> s_waitcnt lgkmcnt(0) -> s_barrier
// VGPR-targeted prefetch loads are guarded by the compiler's precise
// vmcnt(N) waits at their consume sites.
// ---------------------------------------------------------------------------
__device__ __forceinline__ void scan_barrier_nodrain() {
    asm volatile("s_waitcnt lgkmcnt(0)" ::: "memory");
    __builtin_amdgcn_s_barrier();
    asm volatile("" ::: "memory");
}

// ---------------------------------------------------------------------------
// Sequential attractor scan — r22: EXACT r16 structure (the fastest measured
// scan shape: clamped unconditional prefetch, quarter-grain distance THREE,
// 4 named buffers = 128 VGPRs, ping-pong et) with ONLY the barrier swapped
// to the non-draining form. r20/r21's distance-8 regressed because 64
// outstanding VMEM ops exceed the vmcnt cap (63) — the wave stalls at load
// ISSUE instead of at a counted wait. Distance-3 keeps <=24 outstanding.
// Chain is op-for-op the verified sequence: ONE accumulator, strictly
// ascending d (q asc, dq asc, x,y,z,w = d..d+3), non-fused rn ops — bitwise
// contract. Clamped prefetch (pfc) never reads out of bounds.
// ---------------------------------------------------------------------------
#define SCAN_QUARTER(Q, WC, WP)                                             \
    {                                                                       \
        /* UNCONDITIONAL prefetch (clamped): straight-line loads ->         \
           precise vmcnt. Clamped (pf>=nq) loads land in buffers never      \
           consumed. */                                                     \
        const int pf = (ii - start) * 4 + (Q) + 3;                          \
        const int pfc = (pf < nq) ? pf : (nq - 1); /* uniform select */     \
        const float4* P4 = Wb4 + (size_t)(start + (pfc >> 2)) * 4096        \
                               + (size_t)(pfc & 3) * 1024 + e;              \
        _Pragma("unroll")                                                   \
        for (int u = 0; u < 8; ++u) WP[u] = P4[u * 128];                    \
        asm volatile("" ::: "memory");                                      \
        /* consume quarter Q: d = 32Q .. 32Q+31, strictly ascending */      \
        _Pragma("unroll")                                                   \
        for (int dq = 0; dq < 8; ++dq) {                                    \
            const float4 t4 = *(const float4*)&et[s][(Q) * 32 + dq * 4];    \
            const float4 wv = WC[dq]; /* W[d..d+3][e], d = 32Q+4dq */       \
            sum = __fadd_rn(sum, __fmul_rn(t4.x, wv.x));                    \
            sum = __fadd_rn(sum, __fmul_rn(t4.y, wv.y));                    \
            sum = __fadd_rn(sum, __fmul_rn(t4.z, wv.z));                    \
            sum = __fadd_rn(sum, __fmul_rn(t4.w, wv.w));                    \
        }                                                                   \
    }

__global__ __launch_bounds__(128, 1) void scan_kernel(const float* __restrict__ Wa,
                                                      const float* __restrict__ e0,
                                                      float* __restrict__ et_state,
                                                      float* __restrict__ out,
                                                      int i0, int CH) {
    __shared__ float et[2][128];
    const int b = blockIdx.x;
    const int e = threadIdx.x;  // 0..127

    int s = 0;
    if (i0 == 0) {
        const float v = e0[e];
        et[0][e] = v;
        out[(size_t)b * SS * ENC + e] = v;
    } else {
        et[0][e] = et_state[b * 128 + e];
    }
    __syncthreads();   // once, before the pipeline — drain is harmless here

    const int start = (i0 == 0) ? 1 : 0;
    const float4* Wb4 = (const float4*)(Wa + (size_t)b * CH * (ENC * ENC));
    const int nq = (CH - start) * 4;   // total quarter-tiles this launch
    // step stride in float4: ENC*ENC/4 = 4096; quarter stride: 8*128 = 1024

    // 4 quarter buffers x 8 float4 = 128 VGPRs (r13-proven distance 3)
    float4 w0[8], w1[8], w2[8], w3[8];

    // preload quarters 0,1,2 of step `start`
    {
        const float4* S4 = Wb4 + (size_t)start * 4096 + e;
#pragma unroll
        for (int u = 0; u < 8; ++u) w0[u] = S4[u * 128];
#pragma unroll
        for (int u = 0; u < 8; ++u) w1[u] = S4[(8 + u) * 128];
#pragma unroll
        for (int u = 0; u < 8; ++u) w2[u] = S4[(16 + u) * 128];
    }
    asm volatile("" ::: "memory");  // loads pinned before first chain

    for (int ii = start; ii < CH; ++ii) {
        float sum = 0.f;   // ONE accumulator, ascending d across all quarters
        SCAN_QUARTER(0, w0, w3)   // consume q0, prefetch into buffer (0+3)&3=3
        SCAN_QUARTER(1, w1, w0)
        SCAN_QUARTER(2, w2, w1)
        SCAN_QUARTER(3, w3, w2)
        const float v = fminf(fmaxf(sum, -5.f), 5.f);  // jnp.clip
        out[((size_t)b * SS + (i0 + ii)) * ENC + e] = v;
        et[s ^ 1][e] = v;   // this step's readers use et[s] — no conflict
        scan_barrier_nodrain();  // publishes et[s^1]; keeps vmcnt queue alive
        s ^= 1;
    }
    et_state[b * 128 + e] = et[s][e];
}

// ---------------------------------------------------------------------------
extern "C" void kernel_launch(void* const* d_in, const int* in_sizes, int n_in,
                              void* d_out, int out_size, void* d_ws, size_t ws_size,
                              hipStream_t stream) {
    const float* A  = (const float*)d_in[0];  // (B,S,E)   = (8,512,128) fp32
    const float* W1 = (const float*)d_in[1];  // (H,E)     = (512,128)  fp32
    const float* b1 = (const float*)d_in[2];  // (H,)      fp32
    const float* W2 = (const float*)d_in[3];  // (ENC*ENC,H) = (16384,512) fp32
    const float* b2 = (const float*)d_in[4];  // (ENC*ENC,) fp32
    const float* e0 = (const float*)d_in[5];  // (1,ENC)   fp32
    float* out = (float*)d_out;               // (B,S,ENC) fp32

    // Serial r16 schedule (known-good base).
    // Pick the largest chunk CH (steps) whose fp32 workspace fits ws_size.
    // ws layout: [et_state 4KB][hidden_c Mc*512 f32][Wa_c Mc*16384 f32]
    int CH = 16;
    for (int c = 512; c >= 16; c >>= 1) {
        const size_t Mc = (size_t)BB * c;
        const size_t need = 4096 + Mc * HH * sizeof(float) +
                            Mc * (size_t)(ENC * ENC) * sizeof(float);
        if (need <= ws_size) { CH = c; break; }
    }
    const int Mc = BB * CH;
    int chsh = 0;
    while ((1 << chsh) < CH) ++chsh;
    const int chm1 = CH - 1;

    float* et_state = (float*)d_ws;
    float* hidden   = (float*)((char*)d_ws + 4096);
    float* Wa       = hidden + (size_t)Mc * HH;   // d-interleaved layout (Wa4)

    for (int i0 = 0; i0 < SS; i0 += CH) {
        // GEMM1: hidden_c = tanh(A[chunk rows] @ W1^T + b1)  [Mc x 512, K=128]
        dim3 g1(HH / 128, Mc / 128);
        gemm_nt<1, 1, 0><<<g1, 256, 0, stream>>>(A, W1, b1, hidden, HH, EE,
                                                 chm1, chsh, i0);
        // GEMM2: Wa4_c = (hidden_c @ W2^T + b2) stored d-interleaved
        dim3 g2((ENC * ENC) / 128, Mc / 128);
        gemm_nt<0, 0, 1><<<g2, 256, 0, stream>>>(hidden, W2, b2, Wa, ENC * ENC,
                                                 HH, 0, 0, 0);
        // scan this chunk (one workgroup per batch; fp32 state in ws)
        scan_kernel<<<BB, 128, 0, stream>>>(Wa, e0, et_state, out, i0, CH);
    }
}